// Round 13
// baseline (228.546 us; speedup 1.0000x reference)
//
#include <hip/hip_runtime.h>
#include <math.h>

#define NE 8
#define KDIM 4096
#define PDIM 64
#define WROWS (KDIM + PDIM)   // 4160
#define EPS_F32 1.1920929e-07f
#define NCHUNK 16             // 4096 / (64 lanes * 4 floats)
#define TPW 2                 // tokens per wave
#define WAVES 16              // waves per block (1024 threads)
#define ROWF4 (WROWS / 4)     // 1040 f4 per Wt row
#define LDSF4 (NE * ROWF4)    // 8320 f4 = 133120 B of LDS

typedef float f4 __attribute__((ext_vector_type(4)));

// --- tiny setup kernel: W[4160][8] -> Wt[8][4160] in d_ws ---
__global__ __launch_bounds__(256)
void transpose_w(const float* __restrict__ W, float* __restrict__ Wt) {
    const int k = blockIdx.x * 256 + threadIdx.x;
    if (k < WROWS) {
        float v[NE];
#pragma unroll
        for (int e = 0; e < NE; ++e) v[e] = W[(size_t)k * NE + e];
#pragma unroll
        for (int e = 0; e < NE; ++e) Wt[(size_t)e * WROWS + k] = v[e];
    }
}

// R5 shape (the best total: 202.4) with the spill KILLED at its source.
// R9/R10/R12 direct counters show the same signature every time: arch
// VGPRs = exactly half the wave budget (64/128, 128/256) + 110-230 MB
// scratch -> the instruction scheduler hoists load batches across the
// fully-unrolled 16-chunk window (many iterations' 32-reg wb ds_read
// batches + NT x loads), blowing liveness past ANY budget; the allocator
// then spills to AGPRs (halving the file) and scratch. Block size and
// unroll-4 don't stop it.
// FIX: __builtin_amdgcn_sched_barrier(0) at each chunk boundary. The
// depth-2 pipeline is already encoded in PROGRAM ORDER (prefetch c+2 is
// issued inside iteration c, waited on 2 iterations later), so blocking
// cross-iteration scheduler motion keeps the pipeline and pins liveness
// at the designed ring: xb[3][2]=24 + wb 32 transient + acc 16 + addr
// ~20 = ~95 regs, fitting the hard 128/wave cap of a 1024-thread block
// (16 waves/CU = 4/SIMD -- R5's TLP, which beat every 8-wave variant).
__global__ __launch_bounds__(1024, 4)
void topk_gate(const float* __restrict__ x,
               const float* __restrict__ prompt,
               const float* __restrict__ Wt,
               const float* __restrict__ b,
               float* __restrict__ out,
               int tokens)
{
    __shared__ f4 wlds[LDSF4];          // 133120 B

    const int tid  = threadIdx.x;
    const int lane = tid & 63;          // 0..63
    const int wid  = tid >> 6;          // 0..15

    const int tbase = (blockIdx.x * WAVES + wid) * TPW;
    const int phase = (blockIdx.x * 5) & 15;

    const f4* xr0 = (const f4*)(x + (size_t)tbase * KDIM);
    const f4* xr1 = (const f4*)(x + (size_t)(tbase + 1) * KDIM);

    auto cidx = [&](int c) { return ((c + phase) & 15) * 64 + lane; };  // f4 units

    f4 xb[3][TPW];     // depth-2 prefetch ring; static indices under full unroll

    // ---- x prologue FIRST: chunks 0,1 fly while we stage Wt -> LDS ----
    {
        const int k0 = cidx(0);
        xb[0][0] = __builtin_nontemporal_load(xr0 + k0);
        xb[0][1] = __builtin_nontemporal_load(xr1 + k0);
        const int k1 = cidx(1);
        xb[1][0] = __builtin_nontemporal_load(xr0 + k1);
        xb[1][1] = __builtin_nontemporal_load(xr1 + k1);
    }

    // ---- stage Wt -> LDS (linear f4 copy, coalesced, conflict-free) ----
    {
        const f4* wt4 = (const f4*)Wt;
        for (int i = tid; i < LDSF4; i += WAVES * 64)
            wlds[i] = wt4[i];
    }
    __syncthreads();

    float acc[TPW][NE];
#pragma unroll
    for (int t = 0; t < TPW; ++t)
#pragma unroll
        for (int e = 0; e < NE; ++e) acc[t][e] = 0.f;

#pragma unroll
    for (int c = 0; c < NCHUNK; ++c) {
        // Hard scheduling fence: nothing (loads included) may be hoisted
        // across an iteration boundary. This is what caps liveness at the
        // designed ring and prevents the AGPR+scratch spill (R9/R10/R12).
        __builtin_amdgcn_sched_barrier(0);

        if (c + 2 < NCHUNK) {
            const int kx = cidx(c + 2);
            xb[(c + 2) % 3][0] = __builtin_nontemporal_load(xr0 + kx);
            xb[(c + 2) % 3][1] = __builtin_nontemporal_load(xr1 + kx);
        }

        const int kw = cidx(c);
        f4 wb[NE];
#pragma unroll
        for (int e = 0; e < NE; ++e)
            wb[e] = wlds[e * ROWF4 + kw];

        const int s = c % 3;
#pragma unroll
        for (int t = 0; t < TPW; ++t)
#pragma unroll
            for (int e = 0; e < NE; ++e) {
                const f4 xv = xb[s][t];
                acc[t][e] = fmaf(xv.x, wb[e].x, acc[t][e]);
                acc[t][e] = fmaf(xv.y, wb[e].y, acc[t][e]);
                acc[t][e] = fmaf(xv.z, wb[e].z, acc[t][e]);
                acc[t][e] = fmaf(xv.w, wb[e].w, acc[t][e]);
            }
    }
    __builtin_amdgcn_sched_barrier(0);

    // prompt part (64 dims): lanes 0..15, w from LDS f4 cols 1024..1039
    if (lane < 16) {
        f4 pv[TPW];
#pragma unroll
        for (int t = 0; t < TPW; ++t)
            pv[t] = *((const f4*)(prompt + (size_t)(tbase + t) * PDIM) + lane);
#pragma unroll
        for (int e = 0; e < NE; ++e) {
            const f4 wv = wlds[e * ROWF4 + (KDIM / 4) + lane];
#pragma unroll
            for (int t = 0; t < TPW; ++t) {
                acc[t][e] = fmaf(pv[t].x, wv.x, acc[t][e]);
                acc[t][e] = fmaf(pv[t].y, wv.y, acc[t][e]);
                acc[t][e] = fmaf(pv[t].z, wv.z, acc[t][e]);
                acc[t][e] = fmaf(pv[t].w, wv.w, acc[t][e]);
            }
        }
    }

    // butterfly reduce: every lane ends with full logits for both tokens
#pragma unroll
    for (int t = 0; t < TPW; ++t)
#pragma unroll
        for (int e = 0; e < NE; ++e) {
            float v = acc[t][e];
#pragma unroll
            for (int off = 32; off >= 1; off >>= 1)
                v += __shfl_xor(v, off, 64);
            acc[t][e] = v;
        }

    // ---- epilogue: lanes 0..31, lane = tt*16 + kk*8 + ee ----
    const int tt = (lane >> 4) & 1;
    const int kk = (lane >> 3) & 1;
    const int ee = lane & 7;

    float lg[NE];
#pragma unroll
    for (int e = 0; e < NE; ++e) {
        const float v = (tt == 0) ? acc[0][e] : acc[1][e];
        lg[e] = v + b[e];
    }

    // top-2, strict > so smallest index wins ties (jax.lax.top_k semantics)
    float v0 = lg[0]; int i0 = 0;
#pragma unroll
    for (int e = 1; e < NE; ++e)
        if (lg[e] > v0) { v0 = lg[e]; i0 = e; }
    float v1 = (i0 == 0) ? lg[1] : lg[0];
    int   i1 = (i0 == 0) ? 1 : 0;
#pragma unroll
    for (int e = 0; e < NE; ++e)
        if (e != i0 && lg[e] > v1) { v1 = lg[e]; i1 = e; }

    float s = 0.f;
#pragma unroll
    for (int e = 0; e < NE; ++e) s += __expf(lg[e] - v0);
    const float g0 = 1.0f / s;
    const float g1 = __expf(v1 - v0) / s;
    const float denom = fmaxf(g0 + g1, EPS_F32);

    if (lane < 32) {
        const int sel = kk ? i1 : i0;
        const int t_global = tbase + tt;
        out[(size_t)t_global * 16 + kk * 8 + ee] = (ee == sel) ? 1.0f : 0.0f;

        if ((lane & 15) < 2) {
            const float g = (ee == 0) ? (g0 / denom) : (g1 / denom);
            out[(size_t)tokens * 16 + (size_t)t_global * 2 + ee] = g;
        }
    }
}

extern "C" void kernel_launch(void* const* d_in, const int* in_sizes, int n_in,
                              void* d_out, int out_size, void* d_ws, size_t ws_size,
                              hipStream_t stream) {
    const float* x      = (const float*)d_in[0];
    const float* prompt = (const float*)d_in[1];
    const float* W      = (const float*)d_in[2];
    const float* b      = (const float*)d_in[3];
    float* out          = (float*)d_out;
    float* Wt           = (float*)d_ws;          // 8*4160*4 = 133 KB

    const int tokens = in_sizes[0] / KDIM;       // 8192

    hipLaunchKernelGGL(transpose_w, dim3((WROWS + 255) / 256), dim3(256), 0, stream,
                       W, Wt);
    hipLaunchKernelGGL(topk_gate, dim3(tokens / (WAVES * TPW)), dim3(WAVES * 64),
                       0, stream, x, prompt, Wt, b, out, tokens);
}

// Round 14
// 200.181 us; speedup vs baseline: 1.1417x; 1.1417x over previous
//
#include <hip/hip_runtime.h>
#include <math.h>

#define NE 8
#define KDIM 4096
#define PDIM 64
#define WROWS (KDIM + PDIM)   // 4160
#define EPS_F32 1.1920929e-07f
#define NCHUNK 16             // 4096 / (64 lanes * 4 floats)
#define TPW 2                 // tokens per wave
#define WAVES 16              // waves per block (1024 threads)
#define ROWF4 (WROWS / 4)     // 1040 f4 per Wt row
#define LDSF4 (NE * ROWF4)    // 8320 f4 = 133120 B of LDS

typedef float f4 __attribute__((ext_vector_type(4)));

// --- tiny setup kernel: W[4160][8] -> Wt[8][4160] in d_ws ---
__global__ __launch_bounds__(256)
void transpose_w(const float* __restrict__ W, float* __restrict__ Wt) {
    const int k = blockIdx.x * 256 + threadIdx.x;
    if (k < WROWS) {
        float v[NE];
#pragma unroll
        for (int e = 0; e < NE; ++e) v[e] = W[(size_t)k * NE + e];
#pragma unroll
        for (int e = 0; e < NE; ++e) Wt[(size_t)e * WROWS + k] = v[e];
    }
}

// R5 shape (best total: 202.4) with the spill contained STRUCTURALLY:
// the chunk loop is ROLLED (#pragma unroll 1) with named-variable buffer
// rotation instead of a fully-unrolled array ring.
// Why: R9/R10/R12 showed the same spill signature (arch VGPR = half the
// wave budget + AGPR overflow + 100-230 MB scratch) at every block size;
// the fully-unrolled 16-chunk loop lets the scheduler batch loads across
// iterations until liveness exceeds ANY budget. R13's per-iteration
// sched_barrier(0) stopped the batching but also killed in-iteration
// scheduling (m141 lesson) -> slower. A rolled loop makes cross-iteration
// hoisting impossible at the IR level while program order still encodes
// the depth-2 pipeline: load(c+2) issued in iteration c, consumed two
// iterations later -> pre-FMA wait is vmcnt(4), never a drain. Named f4
// rotation (a<=b<=c) keeps all indexing compile-time (rule #20 safe);
// ~8 v_mov/iter vs 64 FMAs is cheap against 110 MB of scratch traffic.
// Liveness by construction: 3 buffer pairs (24) + wb transient (32) +
// acc (16) + addressing (~20) ~= 95 regs < 128 cap (16 waves/CU, 4/SIMD).
__global__ __launch_bounds__(1024, 4)
void topk_gate(const float* __restrict__ x,
               const float* __restrict__ prompt,
               const float* __restrict__ Wt,
               const float* __restrict__ b,
               float* __restrict__ out,
               int tokens)
{
    __shared__ f4 wlds[LDSF4];          // 133120 B

    const int tid  = threadIdx.x;
    const int lane = tid & 63;          // 0..63
    const int wid  = tid >> 6;          // 0..15

    const int tbase = (blockIdx.x * WAVES + wid) * TPW;
    const int phase = (blockIdx.x * 5) & 15;

    const f4* xr0 = (const f4*)(x + (size_t)tbase * KDIM);
    const f4* xr1 = (const f4*)(x + (size_t)(tbase + 1) * KDIM);

    auto cidx = [&](int c) { return ((c + phase) & 15) * 64 + lane; };  // f4 units

    // ---- named depth-2 ring; x(0),x(1) fly while we stage Wt -> LDS ----
    f4 a0, a1, b0, b1;
    {
        const int k0 = cidx(0);
        a0 = __builtin_nontemporal_load(xr0 + k0);
        a1 = __builtin_nontemporal_load(xr1 + k0);
        const int k1 = cidx(1);
        b0 = __builtin_nontemporal_load(xr0 + k1);
        b1 = __builtin_nontemporal_load(xr1 + k1);
    }

    // ---- stage Wt -> LDS (linear f4 copy, coalesced, conflict-free) ----
    {
        const f4* wt4 = (const f4*)Wt;
        for (int i = tid; i < LDSF4; i += WAVES * 64)
            wlds[i] = wt4[i];
    }
    __syncthreads();

    float acc[TPW][NE];
#pragma unroll
    for (int t = 0; t < TPW; ++t)
#pragma unroll
        for (int e = 0; e < NE; ++e) acc[t][e] = 0.f;

#pragma unroll 1
    for (int c = 0; c < NCHUNK; ++c) {
        // prefetch chunk c+2 into the incoming pair (n0,n1)
        f4 n0 = b0, n1 = b1;                 // defined value for the tail
        if (c + 2 < NCHUNK) {
            const int kx = cidx(c + 2);
            n0 = __builtin_nontemporal_load(xr0 + kx);
            n1 = __builtin_nontemporal_load(xr1 + kx);
        }

        // w for the CURRENT chunk from LDS (8x conflict-free ds_read_b128)
        const int kw = cidx(c);
        f4 wb[NE];
#pragma unroll
        for (int e = 0; e < NE; ++e)
            wb[e] = wlds[e * ROWF4 + kw];

#pragma unroll
        for (int e = 0; e < NE; ++e) {
            acc[0][e] = fmaf(a0.x, wb[e].x, acc[0][e]);
            acc[0][e] = fmaf(a0.y, wb[e].y, acc[0][e]);
            acc[0][e] = fmaf(a0.z, wb[e].z, acc[0][e]);
            acc[0][e] = fmaf(a0.w, wb[e].w, acc[0][e]);
            acc[1][e] = fmaf(a1.x, wb[e].x, acc[1][e]);
            acc[1][e] = fmaf(a1.y, wb[e].y, acc[1][e]);
            acc[1][e] = fmaf(a1.z, wb[e].z, acc[1][e]);
            acc[1][e] = fmaf(a1.w, wb[e].w, acc[1][e]);
        }

        // rotate the ring: consumed a <- b <- incoming
        a0 = b0; a1 = b1;
        b0 = n0; b1 = n1;
    }

    // prompt part (64 dims): lanes 0..15, w from LDS f4 cols 1024..1039
    if (lane < 16) {
        f4 pv[TPW];
#pragma unroll
        for (int t = 0; t < TPW; ++t)
            pv[t] = *((const f4*)(prompt + (size_t)(tbase + t) * PDIM) + lane);
#pragma unroll
        for (int e = 0; e < NE; ++e) {
            const f4 wv = wlds[e * ROWF4 + (KDIM / 4) + lane];
#pragma unroll
            for (int t = 0; t < TPW; ++t) {
                acc[t][e] = fmaf(pv[t].x, wv.x, acc[t][e]);
                acc[t][e] = fmaf(pv[t].y, wv.y, acc[t][e]);
                acc[t][e] = fmaf(pv[t].z, wv.z, acc[t][e]);
                acc[t][e] = fmaf(pv[t].w, wv.w, acc[t][e]);
            }
        }
    }

    // butterfly reduce: every lane ends with full logits for both tokens
#pragma unroll
    for (int t = 0; t < TPW; ++t)
#pragma unroll
        for (int e = 0; e < NE; ++e) {
            float v = acc[t][e];
#pragma unroll
            for (int off = 32; off >= 1; off >>= 1)
                v += __shfl_xor(v, off, 64);
            acc[t][e] = v;
        }

    // ---- epilogue: lanes 0..31, lane = tt*16 + kk*8 + ee ----
    const int tt = (lane >> 4) & 1;
    const int kk = (lane >> 3) & 1;
    const int ee = lane & 7;

    float lg[NE];
#pragma unroll
    for (int e = 0; e < NE; ++e) {
        const float v = (tt == 0) ? acc[0][e] : acc[1][e];
        lg[e] = v + b[e];
    }

    // top-2, strict > so smallest index wins ties (jax.lax.top_k semantics)
    float v0 = lg[0]; int i0 = 0;
#pragma unroll
    for (int e = 1; e < NE; ++e)
        if (lg[e] > v0) { v0 = lg[e]; i0 = e; }
    float v1 = (i0 == 0) ? lg[1] : lg[0];
    int   i1 = (i0 == 0) ? 1 : 0;
#pragma unroll
    for (int e = 0; e < NE; ++e)
        if (e != i0 && lg[e] > v1) { v1 = lg[e]; i1 = e; }

    float s = 0.f;
#pragma unroll
    for (int e = 0; e < NE; ++e) s += __expf(lg[e] - v0);
    const float g0 = 1.0f / s;
    const float g1 = __expf(v1 - v0) / s;
    const float denom = fmaxf(g0 + g1, EPS_F32);

    if (lane < 32) {
        const int sel = kk ? i1 : i0;
        const int t_global = tbase + tt;
        out[(size_t)t_global * 16 + kk * 8 + ee] = (ee == sel) ? 1.0f : 0.0f;

        if ((lane & 15) < 2) {
            const float g = (ee == 0) ? (g0 / denom) : (g1 / denom);
            out[(size_t)tokens * 16 + (size_t)t_global * 2 + ee] = g;
        }
    }
}

extern "C" void kernel_launch(void* const* d_in, const int* in_sizes, int n_in,
                              void* d_out, int out_size, void* d_ws, size_t ws_size,
                              hipStream_t stream) {
    const float* x      = (const float*)d_in[0];
    const float* prompt = (const float*)d_in[1];
    const float* W      = (const float*)d_in[2];
    const float* b      = (const float*)d_in[3];
    float* out          = (float*)d_out;
    float* Wt           = (float*)d_ws;          // 8*4160*4 = 133 KB

    const int tokens = in_sizes[0] / KDIM;       // 8192

    hipLaunchKernelGGL(transpose_w, dim3((WROWS + 255) / 256), dim3(256), 0, stream,
                       W, Wt);
    hipLaunchKernelGGL(topk_gate, dim3(tokens / (WAVES * TPW)), dim3(WAVES * 64),
                       0, stream, x, prompt, Wt, b, out, tokens);
}